// Round 1
// baseline (543.356 us; speedup 1.0000x reference)
//
#include <hip/hip_runtime.h>

// CombinedModel: per-point pipeline
//   int_pos = floor(x); nb4 = neighbor_map[i,j]; dist_k = |positions[nb_k] - int_pos|
//   latent[32] = sum_k dist_k * embeddings[nb_k]
//   h1 = relu(latent @ W1^T + b1); h2 = relu(h1 @ W2^T + b2); o = h2 @ W3^T + b3
//   o = o*std + mu; nan -> mu else clip[0,1]
// Baseline: 1 thread per point, fp32, fully unrolled MLP (activations in VGPRs,
// weights via uniform-address loads -> expect s_load promotion).

#define GRID_W 2048

__global__ __launch_bounds__(256, 2) void fused_point_mlp(
    const float* __restrict__ x,          // [N,2]
    const float* __restrict__ positions,  // [N_POS,2]
    const int*   __restrict__ nbmap,      // [H,W,4]
    const float* __restrict__ emb,        // [N_POS,32]
    const float* __restrict__ W1,         // [64,32]
    const float* __restrict__ b1,         // [64]
    const float* __restrict__ W2,         // [64,64]
    const float* __restrict__ b2,         // [64]
    const float* __restrict__ W3,         // [3,64]
    const float* __restrict__ b3,         // [3]
    const float* __restrict__ mu,         // [3]
    const float* __restrict__ sd,         // [3]
    float* __restrict__ out,              // [N,3]
    int npts)
{
    int t = blockIdx.x * 256 + threadIdx.x;
    if (t >= npts) return;

    // --- gather phase ---
    float2 xv = *(const float2*)(x + 2 * (long)t);
    int i0 = (int)floorf(xv.x);
    int i1 = (int)floorf(xv.y);
    float f0 = (float)i0, f1 = (float)i1;

    int4 nb = *(const int4*)(nbmap + ((long)(i0 * GRID_W + i1)) * 4);
    int ids[4] = {nb.x, nb.y, nb.z, nb.w};

    float lat[32];
#pragma unroll
    for (int d = 0; d < 32; ++d) lat[d] = 0.0f;

#pragma unroll
    for (int k = 0; k < 4; ++k) {
        float2 p = *(const float2*)(positions + 2 * (long)ids[k]);
        float dx = p.x - f0, dy = p.y - f1;
        float dist = sqrtf(dx * dx + dy * dy);
        const float4* e = (const float4*)(emb + 32 * (long)ids[k]);
#pragma unroll
        for (int q = 0; q < 8; ++q) {
            float4 v = e[q];
            lat[4 * q + 0] = fmaf(dist, v.x, lat[4 * q + 0]);
            lat[4 * q + 1] = fmaf(dist, v.y, lat[4 * q + 1]);
            lat[4 * q + 2] = fmaf(dist, v.z, lat[4 * q + 2]);
            lat[4 * q + 3] = fmaf(dist, v.w, lat[4 * q + 3]);
        }
    }

    // --- layer 1: 32 -> 64, relu ---
    float h1[64];
#pragma unroll
    for (int n = 0; n < 64; ++n) {
        float a = b1[n];
        const float* w = W1 + n * 32;
#pragma unroll
        for (int k2 = 0; k2 < 32; ++k2) a = fmaf(w[k2], lat[k2], a);
        h1[n] = fmaxf(a, 0.0f);
    }

    // --- layer 2: 64 -> 64, relu ---
    float h2[64];
#pragma unroll
    for (int n = 0; n < 64; ++n) {
        float a = b2[n];
        const float* w = W2 + n * 64;
#pragma unroll
        for (int k2 = 0; k2 < 64; ++k2) a = fmaf(w[k2], h1[k2], a);
        h2[n] = fmaxf(a, 0.0f);
    }

    // --- layer 3: 64 -> 3, affine, nan-guard, clip ---
    float o[3];
#pragma unroll
    for (int m = 0; m < 3; ++m) {
        float a = b3[m];
        const float* w = W3 + m * 64;
#pragma unroll
        for (int k2 = 0; k2 < 64; ++k2) a = fmaf(w[k2], h2[k2], a);
        o[m] = a * sd[m] + mu[m];
    }
    bool any_nan = (o[0] != o[0]) || (o[1] != o[1]) || (o[2] != o[2]);
#pragma unroll
    for (int m = 0; m < 3; ++m) {
        float v = any_nan ? mu[m] : fminf(fmaxf(o[m], 0.0f), 1.0f);
        out[3 * (long)t + m] = v;
    }
}

extern "C" void kernel_launch(void* const* d_in, const int* in_sizes, int n_in,
                              void* d_out, int out_size, void* d_ws, size_t ws_size,
                              hipStream_t stream) {
    const float* x         = (const float*)d_in[0];
    const float* positions = (const float*)d_in[1];
    const int*   nbmap     = (const int*)d_in[2];
    const float* emb       = (const float*)d_in[3];
    const float* W1        = (const float*)d_in[4];
    const float* b1        = (const float*)d_in[5];
    const float* W2        = (const float*)d_in[6];
    const float* b2        = (const float*)d_in[7];
    const float* W3        = (const float*)d_in[8];
    const float* b3        = (const float*)d_in[9];
    const float* mu        = (const float*)d_in[10];
    const float* sd        = (const float*)d_in[11];
    float* out = (float*)d_out;

    int npts = in_sizes[0] / 2;
    int blocks = (npts + 255) / 256;
    fused_point_mlp<<<blocks, 256, 0, stream>>>(x, positions, nbmap, emb,
                                                W1, b1, W2, b2, W3, b3, mu, sd,
                                                out, npts);
}

// Round 2
// 364.343 us; speedup vs baseline: 1.4913x; 1.4913x over previous
//
#include <hip/hip_runtime.h>

// CombinedModel: gather (nbmap -> positions/embeddings) + 3-layer MLP.
// R2: MLP as split-bf16 MFMA (hi/lo, 3-product -> ~1e-4 error), fp32 VALU layer-3.
// Wave-synchronous design: all LDS traffic is wave-local, zero __syncthreads.

typedef __attribute__((ext_vector_type(2))) float f32x2;
typedef __attribute__((ext_vector_type(4))) float f32x4;
typedef __attribute__((ext_vector_type(4))) int   i32x4;
typedef __attribute__((ext_vector_type(4))) short s16x4;
typedef __attribute__((ext_vector_type(8))) short s16x8;

#define GRID_W  2048
#define LAT_STR 36   // 32+4 shorts: 72B row stride -> conflict-free b64 frag reads
#define H1_STR  68   // 64+4 shorts: 136B row stride -> conflict-free b64 frag reads
#define WAVE_SH (64*LAT_STR*2 + 16*H1_STR*2)  // per-wave LDS shorts (lat hi/lo + h1 hi/lo)

__device__ __forceinline__ short bf16_rtn(float x) {
    unsigned u = __float_as_uint(x);
    u += 0x7FFFu + ((u >> 16) & 1u);
    return (short)(u >> 16);
}
__device__ __forceinline__ void split_bf(float x, short &h, short &l) {
    unsigned u = __float_as_uint(x);
    unsigned r = (u + 0x7FFFu + ((u >> 16) & 1u)) & 0xFFFF0000u;
    h = (short)(r >> 16);
    l = bf16_rtn(x - __uint_as_float(r));
}
__device__ __forceinline__ void load_wfrag(const float* p, s16x8 &h, s16x8 &l) {
    f32x4 a = ((const f32x4*)p)[0];
    f32x4 b = ((const f32x4*)p)[1];
    float v[8] = {a.x, a.y, a.z, a.w, b.x, b.y, b.z, b.w};
#pragma unroll
    for (int j = 0; j < 8; ++j) { short hh, ll; split_bf(v[j], hh, ll); h[j] = hh; l[j] = ll; }
}
__device__ __forceinline__ s16x8 lds_read8(const short* p) {
    s16x8 v;
    ((s16x4*)&v)[0] = ((const s16x4*)p)[0];
    ((s16x4*)&v)[1] = ((const s16x4*)p)[1];
    return v;
}
// wave-synchronous LDS fence: stop compiler reordering + drain ds ops
__device__ __forceinline__ void wave_lds_fence() {
    __builtin_amdgcn_wave_barrier();
    __builtin_amdgcn_s_waitcnt(0);
    __builtin_amdgcn_wave_barrier();
}

__global__ __launch_bounds__(128, 2) void fused_point_mlp(
    const float* __restrict__ x,          // [N,2]
    const float* __restrict__ positions,  // [N_POS,2]
    const int*   __restrict__ nbmap,      // [H,W,4]
    const float* __restrict__ emb,        // [N_POS,32]
    const float* __restrict__ W1,         // [64,32]
    const float* __restrict__ b1,         // [64]
    const float* __restrict__ W2,         // [64,64]
    const float* __restrict__ b2,         // [64]
    const float* __restrict__ W3,         // [3,64]
    const float* __restrict__ b3,         // [3]
    const float* __restrict__ mu,         // [3]
    const float* __restrict__ sd,         // [3]
    float* __restrict__ out,              // [N,3]
    int npts)
{
    const int tid  = threadIdx.x;
    const int w    = tid >> 6;
    const int lid  = tid & 63;
    const int quad = lid >> 4;
    const int m16  = lid & 15;
    const int gbase = blockIdx.x * 128;
    if (gbase + (tid & ~63) >= npts) return;   // npts % 64 == 0: whole waves only

    __shared__ short lds_pool[2 * WAVE_SH];
    short* lat_hi = lds_pool + w * WAVE_SH;
    short* lat_lo = lat_hi + 64 * LAT_STR;
    short* h1_hi  = lat_lo + 64 * LAT_STR;
    short* h1_lo  = h1_hi  + 16 * H1_STR;

    // ---- per-wave weight fragments (VGPR-resident, split bf16) ----
    // B-frag for 16x16x32: lane holds B[k = quad*8+j][n = m16]  (k-map cancels A vs B)
    s16x8 w1h[4], w1l[4];
#pragma unroll
    for (int nt = 0; nt < 4; ++nt)
        load_wfrag(W1 + (nt * 16 + m16) * 32 + quad * 8, w1h[nt], w1l[nt]);
    s16x8 w2h[2][4], w2l[2][4];
#pragma unroll
    for (int s = 0; s < 2; ++s)
#pragma unroll
        for (int nt = 0; nt < 4; ++nt)
            load_wfrag(W2 + (nt * 16 + m16) * 64 + s * 32 + quad * 8, w2h[s][nt], w2l[s][nt]);

    float b1v[4], b2v[4], w3v[4][3];
#pragma unroll
    for (int nt = 0; nt < 4; ++nt) {
        b1v[nt] = b1[nt * 16 + m16];
        b2v[nt] = b2[nt * 16 + m16];
#pragma unroll
        for (int m = 0; m < 3; ++m) w3v[nt][m] = W3[m * 64 + nt * 16 + m16];
    }
    const int mm_ = m16 % 3;
    const int rr_ = m16 / 3;
    const float b3m = b3[mm_], sdm = sd[mm_], mum = mu[mm_];

    // ---- phase A: gather + latent[32], one thread per point ----
    {
        const int p = gbase + tid;
        f32x2 xv = ((const f32x2*)x)[p];
        int i0 = (int)xv.x, i1 = (int)xv.y;   // x >= 0 -> trunc == floor
        float f0 = (float)i0, f1 = (float)i1;
        i32x4 nb = ((const i32x4*)nbmap)[i0 * GRID_W + i1];
        int ids[4] = {nb.x, nb.y, nb.z, nb.w};

        float lat[32];
#pragma unroll
        for (int d = 0; d < 32; ++d) lat[d] = 0.0f;
#pragma unroll
        for (int k = 0; k < 4; ++k) {
            f32x2 pp = ((const f32x2*)positions)[ids[k]];
            float dx = pp.x - f0, dy = pp.y - f1;
            float dist = sqrtf(dx * dx + dy * dy);
            const f32x4* er = (const f32x4*)(emb + ids[k] * 32);
#pragma unroll
            for (int q = 0; q < 8; ++q) {
                f32x4 e = er[q];
                lat[4 * q + 0] = fmaf(dist, e.x, lat[4 * q + 0]);
                lat[4 * q + 1] = fmaf(dist, e.y, lat[4 * q + 1]);
                lat[4 * q + 2] = fmaf(dist, e.z, lat[4 * q + 2]);
                lat[4 * q + 3] = fmaf(dist, e.w, lat[4 * q + 3]);
            }
        }
        short* rh = lat_hi + lid * LAT_STR;
        short* rl = lat_lo + lid * LAT_STR;
#pragma unroll
        for (int q = 0; q < 8; ++q) {
            s16x4 sh, sl;
#pragma unroll
            for (int j = 0; j < 4; ++j) { short hh, ll; split_bf(lat[4 * q + j], hh, ll); sh[j] = hh; sl[j] = ll; }
            *(s16x4*)(rh + q * 4) = sh;
            *(s16x4*)(rl + q * 4) = sl;
        }
    }
    wave_lds_fence();

    // ---- phase B: 4 tiles of 16 points per wave ----
    const int outbase = (gbase + w * 64) * 3;
#pragma unroll 1
    for (int t = 0; t < 4; ++t) {
        // L1: latent[16x32] @ W1^T -> h1[16x64]
        const short* ar = lat_hi + (t * 16 + m16) * LAT_STR + quad * 8;
        const short* al_ = lat_lo + (t * 16 + m16) * LAT_STR + quad * 8;
        s16x8 ah = lds_read8(ar);
        s16x8 al = lds_read8(al_);
        f32x4 c1[4];
#pragma unroll
        for (int nt = 0; nt < 4; ++nt) {
            f32x4 c = {0.f, 0.f, 0.f, 0.f};
            c = __builtin_amdgcn_mfma_f32_16x16x32_bf16(ah, w1l[nt], c, 0, 0, 0);
            c = __builtin_amdgcn_mfma_f32_16x16x32_bf16(al, w1h[nt], c, 0, 0, 0);
            c = __builtin_amdgcn_mfma_f32_16x16x32_bf16(ah, w1h[nt], c, 0, 0, 0);
            c1[nt] = c;
        }
        __builtin_amdgcn_wave_barrier();   // WAR: previous tile's h1 reads precede writes
#pragma unroll
        for (int nt = 0; nt < 4; ++nt)
#pragma unroll
            for (int r = 0; r < 4; ++r) {
                float v = fmaxf(c1[nt][r] + b1v[nt], 0.f);
                short hh, ll; split_bf(v, hh, ll);
                int off = (quad * 4 + r) * H1_STR + nt * 16 + m16;
                h1_hi[off] = hh; h1_lo[off] = ll;
            }
        wave_lds_fence();

        // L2: h1[16x64] @ W2^T -> h2[16x64]
        f32x4 c2[4] = {{0.f,0.f,0.f,0.f},{0.f,0.f,0.f,0.f},{0.f,0.f,0.f,0.f},{0.f,0.f,0.f,0.f}};
#pragma unroll
        for (int s = 0; s < 2; ++s) {
            s16x8 a2h = lds_read8(h1_hi + m16 * H1_STR + s * 32 + quad * 8);
            s16x8 a2l = lds_read8(h1_lo + m16 * H1_STR + s * 32 + quad * 8);
#pragma unroll
            for (int nt = 0; nt < 4; ++nt) {
                c2[nt] = __builtin_amdgcn_mfma_f32_16x16x32_bf16(a2h, w2l[s][nt], c2[nt], 0, 0, 0);
                c2[nt] = __builtin_amdgcn_mfma_f32_16x16x32_bf16(a2l, w2h[s][nt], c2[nt], 0, 0, 0);
                c2[nt] = __builtin_amdgcn_mfma_f32_16x16x32_bf16(a2h, w2h[s][nt], c2[nt], 0, 0, 0);
            }
        }

        // L3 in fp32 VALU: out[pt][m] = sum_n h2[pt][n]*W3[m][n] (+b3), butterfly over m16
        float pa[4][3];
#pragma unroll
        for (int r = 0; r < 4; ++r) { pa[r][0] = 0.f; pa[r][1] = 0.f; pa[r][2] = 0.f; }
#pragma unroll
        for (int nt = 0; nt < 4; ++nt)
#pragma unroll
            for (int r = 0; r < 4; ++r) {
                float hv = fmaxf(c2[nt][r] + b2v[nt], 0.f);
                pa[r][0] = fmaf(hv, w3v[nt][0], pa[r][0]);
                pa[r][1] = fmaf(hv, w3v[nt][1], pa[r][1]);
                pa[r][2] = fmaf(hv, w3v[nt][2], pa[r][2]);
            }
#pragma unroll
        for (int r = 0; r < 4; ++r)
#pragma unroll
            for (int m = 0; m < 3; ++m) {
                float v = pa[r][m];
                v += __shfl_xor(v, 1, 64);
                v += __shfl_xor(v, 2, 64);
                v += __shfl_xor(v, 4, 64);
                v += __shfl_xor(v, 8, 64);
                pa[r][m] = v;
            }
        // lane m16 = 3*r+m (m16<12) writes out dword: coalesced 48-dword runs
        float psel = pa[0][0];
#pragma unroll
        for (int r = 0; r < 4; ++r)
#pragma unroll
            for (int m = 0; m < 3; ++m)
                psel = (m16 == 3 * r + m) ? pa[r][m] : psel;
        if (m16 < 12) {
            float v = psel + b3m;
            v = v * sdm + mum;
            v = fminf(fmaxf(v, 0.f), 1.f);   // inputs finite -> no NaN path
            out[outbase + t * 48 + quad * 12 + m16] = v;
        }
        __builtin_amdgcn_wave_barrier();   // keep next tile's LDS writes after reads
    }
}

extern "C" void kernel_launch(void* const* d_in, const int* in_sizes, int n_in,
                              void* d_out, int out_size, void* d_ws, size_t ws_size,
                              hipStream_t stream) {
    const float* x         = (const float*)d_in[0];
    const float* positions = (const float*)d_in[1];
    const int*   nbmap     = (const int*)d_in[2];
    const float* emb       = (const float*)d_in[3];
    const float* W1        = (const float*)d_in[4];
    const float* b1        = (const float*)d_in[5];
    const float* W2        = (const float*)d_in[6];
    const float* b2        = (const float*)d_in[7];
    const float* W3        = (const float*)d_in[8];
    const float* b3        = (const float*)d_in[9];
    const float* mu        = (const float*)d_in[10];
    const float* sd        = (const float*)d_in[11];
    float* out = (float*)d_out;

    int npts = in_sizes[0] / 2;
    int blocks = (npts + 127) / 128;
    fused_point_mlp<<<blocks, 128, 0, stream>>>(x, positions, nbmap, emb,
                                                W1, b1, W2, b2, W3, b3, mu, sd,
                                                out, npts);
}

// Round 3
// 311.497 us; speedup vs baseline: 1.7443x; 1.1697x over previous
//
#include <hip/hip_runtime.h>
#include <hip/hip_bf16.h>

// CombinedModel R3: 3-kernel pipeline through d_ws.
//   K0 prep_weights: split W1/W2/W3(pad 16x64) -> bf16 hi/lo planes in ws.
//   K1 gather_latent: 8 lanes per point (coalesced 128B emb rows), split-bf16
//                     latent -> ws [hi 64B | lo 64B] per point.
//   K2 mlp_mfma: full-split bf16 MFMA for L1/L2/L3 (42 MFMA per 16-pt tile),
//                wave-local packed LDS for h1/h2, no __syncthreads.
// Fallback: R2 fused kernel when ws_size too small.

typedef __attribute__((ext_vector_type(2))) float f32x2;
typedef __attribute__((ext_vector_type(4))) float f32x4;
typedef __attribute__((ext_vector_type(4))) int   i32x4;
typedef __attribute__((ext_vector_type(4))) short s16x4;
typedef __attribute__((ext_vector_type(8))) short s16x8;
typedef __attribute__((ext_vector_type(2))) unsigned u32x2;

#define GRID_W 2048
#define PSTR   68          // packed h-buffer row stride (dwords); 272B = 17*16 -> aligned b128
#define SEL_HI 0x05040100u // v_perm: take low16 of (b,a) -> (hi(e0),hi(e1))
#define SEL_LO 0x07060302u // v_perm: take high16 of (b,a) -> (lo(e0),lo(e1))

static __device__ __forceinline__ unsigned bits_bf2(__hip_bfloat162 h) {
    union { __hip_bfloat162 b; unsigned u; } cv; cv.b = h; return cv.u;
}
// split v into bf16 hi + bf16 lo (lo = rtn(v - hi)); packed dword = hi | lo<<16
static __device__ __forceinline__ void split2_packed(float v0, float v1, unsigned &p0, unsigned &p1) {
    float2 f; f.x = v0; f.y = v1;
    unsigned hu = bits_bf2(__float22bfloat162_rn(f));
    float2 d;
    d.x = v0 - __uint_as_float(hu << 16);
    d.y = v1 - __uint_as_float(hu & 0xffff0000u);
    unsigned lu = bits_bf2(__float22bfloat162_rn(d));
    p0 = (hu & 0xffffu) | (lu << 16);
    p1 = (hu >> 16) | (lu & 0xffff0000u);
}
// same but planar: hi01 = (hi(v0),hi(v1)), lo01 = (lo(v0),lo(v1))
static __device__ __forceinline__ void split2_planes(float v0, float v1, unsigned &hi01, unsigned &lo01) {
    float2 f; f.x = v0; f.y = v1;
    unsigned hu = bits_bf2(__float22bfloat162_rn(f));
    float2 d;
    d.x = v0 - __uint_as_float(hu << 16);
    d.y = v1 - __uint_as_float(hu & 0xffff0000u);
    hi01 = hu;
    lo01 = bits_bf2(__float22bfloat162_rn(d));
}
static __device__ __forceinline__ s16x8 unpack8(uint4 q0, uint4 q1, unsigned sel) {
    union { unsigned u[4]; s16x8 v; } r;
    r.u[0] = __builtin_amdgcn_perm(q0.y, q0.x, sel);
    r.u[1] = __builtin_amdgcn_perm(q0.w, q0.z, sel);
    r.u[2] = __builtin_amdgcn_perm(q1.y, q1.x, sel);
    r.u[3] = __builtin_amdgcn_perm(q1.w, q1.z, sel);
    return r.v;
}

// ---------------- K0: weight prep ----------------
__global__ __launch_bounds__(256) void prep_weights(
    const float* __restrict__ W1, const float* __restrict__ W2, const float* __restrict__ W3,
    unsigned* __restrict__ w1hi, unsigned* __restrict__ w1lo,
    unsigned* __restrict__ w2hi, unsigned* __restrict__ w2lo,
    unsigned* __restrict__ w3hi, unsigned* __restrict__ w3lo)
{
    int t = threadIdx.x;
    for (int i = t; i < 1024; i += 256) split2_planes(W1[2*i], W1[2*i+1], w1hi[i], w1lo[i]);
    for (int i = t; i < 2048; i += 256) split2_planes(W2[2*i], W2[2*i+1], w2hi[i], w2lo[i]);
    for (int i = t; i < 512;  i += 256) {   // W3 zero-padded to [16][64] flat
        int e0 = 2*i, e1 = 2*i+1;
        float v0 = (e0 < 192) ? W3[e0] : 0.0f;
        float v1 = (e1 < 192) ? W3[e1] : 0.0f;
        split2_planes(v0, v1, w3hi[i], w3lo[i]);
    }
}

// ---------------- K1: gather, 8 lanes per point ----------------
__global__ __launch_bounds__(256, 8) void gather_latent(
    const float* __restrict__ x, const float* __restrict__ positions,
    const int* __restrict__ nbmap, const float* __restrict__ emb,
    unsigned char* __restrict__ lat, int npts)
{
    int gt = blockIdx.x * 256 + threadIdx.x;
    int p = gt >> 3, c = gt & 7;
    if (p >= npts) return;
    f32x2 xv = ((const f32x2*)x)[p];
    int i0 = (int)xv.x, i1 = (int)xv.y;          // x >= 0: trunc == floor
    float f0 = (float)i0, f1 = (float)i1;
    i32x4 nb = ((const i32x4*)nbmap)[i0 * GRID_W + i1];
    int ids[4] = {nb.x, nb.y, nb.z, nb.w};
    float a0 = 0.f, a1 = 0.f, a2 = 0.f, a3 = 0.f;
#pragma unroll
    for (int k = 0; k < 4; ++k) {
        f32x2 pp = ((const f32x2*)positions)[ids[k]];
        float dx = pp.x - f0, dy = pp.y - f1;
        float dist = sqrtf(dx * dx + dy * dy);
        f32x4 e = *(const f32x4*)(emb + ids[k] * 32 + c * 4); // 8 lanes -> contiguous 128B
        a0 = fmaf(dist, e.x, a0); a1 = fmaf(dist, e.y, a1);
        a2 = fmaf(dist, e.z, a2); a3 = fmaf(dist, e.w, a3);
    }
    unsigned h01, l01, h23, l23;
    split2_planes(a0, a1, h01, l01);
    split2_planes(a2, a3, h23, l23);
    u32x2 hv; hv.x = h01; hv.y = h23;
    u32x2 lv; lv.x = l01; lv.y = l23;
    *(u32x2*)(lat + (size_t)p * 128 + c * 8) = hv;        // hi plane [0,64)
    *(u32x2*)(lat + (size_t)p * 128 + 64 + c * 8) = lv;   // lo plane [64,128)
}

// ---------------- K2: MFMA MLP ----------------
__global__ __launch_bounds__(256, 2) void mlp_mfma(
    const unsigned char* __restrict__ lat,
    const unsigned* __restrict__ w1hi, const unsigned* __restrict__ w1lo,
    const unsigned* __restrict__ w2hi, const unsigned* __restrict__ w2lo,
    const unsigned* __restrict__ w3hi, const unsigned* __restrict__ w3lo,
    const float* __restrict__ b1, const float* __restrict__ b2,
    const float* __restrict__ b3, const float* __restrict__ mu, const float* __restrict__ sd,
    float* __restrict__ out, int npts)
{
    const int tid = threadIdx.x, w = tid >> 6, lid = tid & 63;
    const int quad = lid >> 4, m16 = lid & 15;
    const int tb = (blockIdx.x * 4 + w) * 64;
    if (tb >= npts) return;                    // whole-wave early exit; no block sync anywhere
    __shared__ __align__(16) unsigned hbuf[4 * 16 * PSTR];
    unsigned* hb = hbuf + w * 16 * PSTR;       // wave-private packed h-buffer (16 rows)

    const uint4* latq = (const uint4*)lat;
    uint4 ahr[2], alr[2];
    {
        int idx = (tb + m16) * 8 + quad;       // (pt*128 + quad*16)/16
        ahr[0] = latq[idx]; alr[0] = latq[idx + 4];
    }
    // weight fragments (B-layout: lane holds B[k=quad*8+j][n=m16])
    s16x8 w1h[4], w1l[4];
#pragma unroll
    for (int nt = 0; nt < 4; ++nt) {
        int fi = (nt * 16 + m16) * 4 + quad;
        w1h[nt] = ((const s16x8*)w1hi)[fi];
        w1l[nt] = ((const s16x8*)w1lo)[fi];
    }
    s16x8 w2h[2][4], w2l[2][4];
#pragma unroll
    for (int s = 0; s < 2; ++s)
#pragma unroll
        for (int nt = 0; nt < 4; ++nt) {
            int fi = (nt * 16 + m16) * 8 + s * 4 + quad;
            w2h[s][nt] = ((const s16x8*)w2hi)[fi];
            w2l[s][nt] = ((const s16x8*)w2lo)[fi];
        }
    s16x8 w3h[2], w3l[2];
#pragma unroll
    for (int s = 0; s < 2; ++s) {
        int fi = m16 * 8 + s * 4 + quad;
        w3h[s] = ((const s16x8*)w3hi)[fi];
        w3l[s] = ((const s16x8*)w3lo)[fi];
    }
    float b1v[4], b2v[4];
#pragma unroll
    for (int nt = 0; nt < 4; ++nt) { b1v[nt] = b1[nt * 16 + m16]; b2v[nt] = b2[nt * 16 + m16]; }
    const int mm = (m16 < 3) ? m16 : 0;
    const float b3m = b3[mm], sdm = sd[mm], mum = mu[mm];

#pragma unroll
    for (int t = 0; t < 4; ++t) {
        if (t < 3) {  // prefetch next tile's A-frags (L3 latency hiding)
            int idx = (tb + (t + 1) * 16 + m16) * 8 + quad;
            ahr[(t + 1) & 1] = latq[idx]; alr[(t + 1) & 1] = latq[idx + 4];
        }
        s16x8 ah = *(s16x8*)&ahr[t & 1];
        s16x8 al = *(s16x8*)&alr[t & 1];
        // L1: latent[16x32] @ W1^T, split 3-product
        f32x4 c1[4];
#pragma unroll
        for (int nt = 0; nt < 4; ++nt) {
            f32x4 c = {0.f, 0.f, 0.f, 0.f};
            c = __builtin_amdgcn_mfma_f32_16x16x32_bf16(ah, w1l[nt], c, 0, 0, 0);
            c = __builtin_amdgcn_mfma_f32_16x16x32_bf16(al, w1h[nt], c, 0, 0, 0);
            c = __builtin_amdgcn_mfma_f32_16x16x32_bf16(ah, w1h[nt], c, 0, 0, 0);
            c1[nt] = c;
        }
        __builtin_amdgcn_wave_barrier();
#pragma unroll
        for (int nt = 0; nt < 4; ++nt)
#pragma unroll
            for (int r = 0; r < 4; r += 2) {
                float v0 = fmaxf(c1[nt][r]     + b1v[nt], 0.f);
                float v1 = fmaxf(c1[nt][r + 1] + b1v[nt], 0.f);
                unsigned p0, p1; split2_packed(v0, v1, p0, p1);
                hb[(quad * 4 + r)     * PSTR + nt * 16 + m16] = p0;
                hb[(quad * 4 + r + 1) * PSTR + nt * 16 + m16] = p1;
            }
        __builtin_amdgcn_wave_barrier();
        // L2: h1[16x64] @ W2^T, split 3-product
        f32x4 c2[4] = {{0.f,0.f,0.f,0.f},{0.f,0.f,0.f,0.f},{0.f,0.f,0.f,0.f},{0.f,0.f,0.f,0.f}};
#pragma unroll
        for (int s = 0; s < 2; ++s) {
            const unsigned* rp = hb + m16 * PSTR + s * 32 + quad * 8;
            uint4 q0 = *(const uint4*)rp;
            uint4 q1 = *(const uint4*)(rp + 4);
            s16x8 a2h = unpack8(q0, q1, SEL_HI);
            s16x8 a2l = unpack8(q0, q1, SEL_LO);
#pragma unroll
            for (int nt = 0; nt < 4; ++nt) {
                c2[nt] = __builtin_amdgcn_mfma_f32_16x16x32_bf16(a2h, w2l[s][nt], c2[nt], 0, 0, 0);
                c2[nt] = __builtin_amdgcn_mfma_f32_16x16x32_bf16(a2l, w2h[s][nt], c2[nt], 0, 0, 0);
                c2[nt] = __builtin_amdgcn_mfma_f32_16x16x32_bf16(a2h, w2h[s][nt], c2[nt], 0, 0, 0);
            }
        }
        __builtin_amdgcn_wave_barrier();
        // h2 -> same buffer (wave DS pipe is in-order; reads above precede these writes)
#pragma unroll
        for (int nt = 0; nt < 4; ++nt)
#pragma unroll
            for (int r = 0; r < 4; r += 2) {
                float v0 = fmaxf(c2[nt][r]     + b2v[nt], 0.f);
                float v1 = fmaxf(c2[nt][r + 1] + b2v[nt], 0.f);
                unsigned p0, p1; split2_packed(v0, v1, p0, p1);
                hb[(quad * 4 + r)     * PSTR + nt * 16 + m16] = p0;
                hb[(quad * 4 + r + 1) * PSTR + nt * 16 + m16] = p1;
            }
        __builtin_amdgcn_wave_barrier();
        // L3: h2[16x64] @ W3p^T (cols 0..2 valid), split 3-product
        f32x4 c3 = {0.f, 0.f, 0.f, 0.f};
#pragma unroll
        for (int s = 0; s < 2; ++s) {
            const unsigned* rp = hb + m16 * PSTR + s * 32 + quad * 8;
            uint4 q0 = *(const uint4*)rp;
            uint4 q1 = *(const uint4*)(rp + 4);
            s16x8 a3h = unpack8(q0, q1, SEL_HI);
            s16x8 a3l = unpack8(q0, q1, SEL_LO);
            c3 = __builtin_amdgcn_mfma_f32_16x16x32_bf16(a3h, w3l[s], c3, 0, 0, 0);
            c3 = __builtin_amdgcn_mfma_f32_16x16x32_bf16(a3l, w3h[s], c3, 0, 0, 0);
            c3 = __builtin_amdgcn_mfma_f32_16x16x32_bf16(a3h, w3h[s], c3, 0, 0, 0);
        }
        __builtin_amdgcn_wave_barrier();
#pragma unroll
        for (int r = 0; r < 4; ++r) {
            float v = (c3[r] + b3m) * sdm + mum;
            v = fminf(fmaxf(v, 0.f), 1.f);     // finite inputs: no NaN path
            if (m16 < 3) out[(size_t)(tb + t * 16 + quad * 4 + r) * 3 + m16] = v;
        }
    }
}

// ---------------- fallback: R2 fused kernel (ws too small) ----------------
#define LAT_STR 36
#define H1_STR  68
#define WAVE_SH (64*LAT_STR*2 + 16*H1_STR*2)

static __device__ __forceinline__ short bf16_rtn(float x) {
    unsigned u = __float_as_uint(x);
    u += 0x7FFFu + ((u >> 16) & 1u);
    return (short)(u >> 16);
}
static __device__ __forceinline__ void split_bf(float x, short &h, short &l) {
    unsigned u = __float_as_uint(x);
    unsigned r = (u + 0x7FFFu + ((u >> 16) & 1u)) & 0xFFFF0000u;
    h = (short)(r >> 16);
    l = bf16_rtn(x - __uint_as_float(r));
}
static __device__ __forceinline__ void load_wfrag(const float* p, s16x8 &h, s16x8 &l) {
    f32x4 a = ((const f32x4*)p)[0];
    f32x4 b = ((const f32x4*)p)[1];
    float v[8] = {a.x, a.y, a.z, a.w, b.x, b.y, b.z, b.w};
#pragma unroll
    for (int j = 0; j < 8; ++j) { short hh, ll; split_bf(v[j], hh, ll); h[j] = hh; l[j] = ll; }
}
static __device__ __forceinline__ s16x8 lds_read8(const short* p) {
    s16x8 v;
    ((s16x4*)&v)[0] = ((const s16x4*)p)[0];
    ((s16x4*)&v)[1] = ((const s16x4*)p)[1];
    return v;
}
static __device__ __forceinline__ void wave_lds_fence() {
    __builtin_amdgcn_wave_barrier();
    __builtin_amdgcn_s_waitcnt(0);
    __builtin_amdgcn_wave_barrier();
}

__global__ __launch_bounds__(128, 2) void fused_fallback(
    const float* __restrict__ x, const float* __restrict__ positions,
    const int* __restrict__ nbmap, const float* __restrict__ emb,
    const float* __restrict__ W1, const float* __restrict__ b1,
    const float* __restrict__ W2, const float* __restrict__ b2,
    const float* __restrict__ W3, const float* __restrict__ b3,
    const float* __restrict__ mu, const float* __restrict__ sd,
    float* __restrict__ out, int npts)
{
    const int tid = threadIdx.x;
    const int w = tid >> 6, lid = tid & 63, quad = lid >> 4, m16 = lid & 15;
    const int gbase = blockIdx.x * 128;
    if (gbase + (tid & ~63) >= npts) return;
    __shared__ short lds_pool[2 * WAVE_SH];
    short* lat_hi = lds_pool + w * WAVE_SH;
    short* lat_lo = lat_hi + 64 * LAT_STR;
    short* h1_hi  = lat_lo + 64 * LAT_STR;
    short* h1_lo  = h1_hi  + 16 * H1_STR;
    s16x8 w1h[4], w1l[4];
#pragma unroll
    for (int nt = 0; nt < 4; ++nt) load_wfrag(W1 + (nt*16 + m16)*32 + quad*8, w1h[nt], w1l[nt]);
    s16x8 w2h[2][4], w2l[2][4];
#pragma unroll
    for (int s = 0; s < 2; ++s)
#pragma unroll
        for (int nt = 0; nt < 4; ++nt)
            load_wfrag(W2 + (nt*16 + m16)*64 + s*32 + quad*8, w2h[s][nt], w2l[s][nt]);
    float b1v[4], b2v[4], w3v[4][3];
#pragma unroll
    for (int nt = 0; nt < 4; ++nt) {
        b1v[nt] = b1[nt*16 + m16]; b2v[nt] = b2[nt*16 + m16];
#pragma unroll
        for (int m = 0; m < 3; ++m) w3v[nt][m] = W3[m*64 + nt*16 + m16];
    }
    const int mm_ = m16 % 3;
    const float b3m = b3[mm_], sdm = sd[mm_], mum = mu[mm_];
    {
        const int p = gbase + tid;
        f32x2 xv = ((const f32x2*)x)[p];
        int i0 = (int)xv.x, i1 = (int)xv.y;
        float f0 = (float)i0, f1 = (float)i1;
        i32x4 nb = ((const i32x4*)nbmap)[i0 * GRID_W + i1];
        int ids[4] = {nb.x, nb.y, nb.z, nb.w};
        float latv[32];
#pragma unroll
        for (int d = 0; d < 32; ++d) latv[d] = 0.0f;
#pragma unroll
        for (int k = 0; k < 4; ++k) {
            f32x2 pp = ((const f32x2*)positions)[ids[k]];
            float dx = pp.x - f0, dy = pp.y - f1;
            float dist = sqrtf(dx*dx + dy*dy);
            const f32x4* er = (const f32x4*)(emb + ids[k]*32);
#pragma unroll
            for (int q = 0; q < 8; ++q) {
                f32x4 e = er[q];
                latv[4*q+0] = fmaf(dist, e.x, latv[4*q+0]);
                latv[4*q+1] = fmaf(dist, e.y, latv[4*q+1]);
                latv[4*q+2] = fmaf(dist, e.z, latv[4*q+2]);
                latv[4*q+3] = fmaf(dist, e.w, latv[4*q+3]);
            }
        }
        short* rh = lat_hi + lid * LAT_STR;
        short* rl = lat_lo + lid * LAT_STR;
#pragma unroll
        for (int q = 0; q < 8; ++q) {
            s16x4 sh, sl;
#pragma unroll
            for (int j = 0; j < 4; ++j) { short hh, ll; split_bf(latv[4*q+j], hh, ll); sh[j] = hh; sl[j] = ll; }
            *(s16x4*)(rh + q*4) = sh;
            *(s16x4*)(rl + q*4) = sl;
        }
    }
    wave_lds_fence();
    const int outbase = (gbase + w * 64) * 3;
#pragma unroll 1
    for (int t = 0; t < 4; ++t) {
        s16x8 ah = lds_read8(lat_hi + (t*16 + m16)*LAT_STR + quad*8);
        s16x8 al = lds_read8(lat_lo + (t*16 + m16)*LAT_STR + quad*8);
        f32x4 c1[4];
#pragma unroll
        for (int nt = 0; nt < 4; ++nt) {
            f32x4 c = {0.f, 0.f, 0.f, 0.f};
            c = __builtin_amdgcn_mfma_f32_16x16x32_bf16(ah, w1l[nt], c, 0, 0, 0);
            c = __builtin_amdgcn_mfma_f32_16x16x32_bf16(al, w1h[nt], c, 0, 0, 0);
            c = __builtin_amdgcn_mfma_f32_16x16x32_bf16(ah, w1h[nt], c, 0, 0, 0);
            c1[nt] = c;
        }
        __builtin_amdgcn_wave_barrier();
#pragma unroll
        for (int nt = 0; nt < 4; ++nt)
#pragma unroll
            for (int r = 0; r < 4; ++r) {
                float v = fmaxf(c1[nt][r] + b1v[nt], 0.f);
                short hh, ll; split_bf(v, hh, ll);
                int off = (quad*4 + r)*H1_STR + nt*16 + m16;
                h1_hi[off] = hh; h1_lo[off] = ll;
            }
        wave_lds_fence();
        f32x4 c2[4] = {{0.f,0.f,0.f,0.f},{0.f,0.f,0.f,0.f},{0.f,0.f,0.f,0.f},{0.f,0.f,0.f,0.f}};
#pragma unroll
        for (int s = 0; s < 2; ++s) {
            s16x8 a2h = lds_read8(h1_hi + m16*H1_STR + s*32 + quad*8);
            s16x8 a2l = lds_read8(h1_lo + m16*H1_STR + s*32 + quad*8);
#pragma unroll
            for (int nt = 0; nt < 4; ++nt) {
                c2[nt] = __builtin_amdgcn_mfma_f32_16x16x32_bf16(a2h, w2l[s][nt], c2[nt], 0, 0, 0);
                c2[nt] = __builtin_amdgcn_mfma_f32_16x16x32_bf16(a2l, w2h[s][nt], c2[nt], 0, 0, 0);
                c2[nt] = __builtin_amdgcn_mfma_f32_16x16x32_bf16(a2h, w2h[s][nt], c2[nt], 0, 0, 0);
            }
        }
        float pa[4][3];
#pragma unroll
        for (int r = 0; r < 4; ++r) { pa[r][0] = 0.f; pa[r][1] = 0.f; pa[r][2] = 0.f; }
#pragma unroll
        for (int nt = 0; nt < 4; ++nt)
#pragma unroll
            for (int r = 0; r < 4; ++r) {
                float hv = fmaxf(c2[nt][r] + b2v[nt], 0.f);
                pa[r][0] = fmaf(hv, w3v[nt][0], pa[r][0]);
                pa[r][1] = fmaf(hv, w3v[nt][1], pa[r][1]);
                pa[r][2] = fmaf(hv, w3v[nt][2], pa[r][2]);
            }
#pragma unroll
        for (int r = 0; r < 4; ++r)
#pragma unroll
            for (int m = 0; m < 3; ++m) {
                float v = pa[r][m];
                v += __shfl_xor(v, 1, 64);
                v += __shfl_xor(v, 2, 64);
                v += __shfl_xor(v, 4, 64);
                v += __shfl_xor(v, 8, 64);
                pa[r][m] = v;
            }
        float psel = pa[0][0];
#pragma unroll
        for (int r = 0; r < 4; ++r)
#pragma unroll
            for (int m = 0; m < 3; ++m)
                psel = (m16 == 3*r + m) ? pa[r][m] : psel;
        if (m16 < 12) {
            float v = psel + b3m;
            v = v * sdm + mum;
            v = fminf(fmaxf(v, 0.f), 1.f);
            out[outbase + t*48 + quad*12 + m16] = v;
        }
        __builtin_amdgcn_wave_barrier();
    }
}

extern "C" void kernel_launch(void* const* d_in, const int* in_sizes, int n_in,
                              void* d_out, int out_size, void* d_ws, size_t ws_size,
                              hipStream_t stream) {
    const float* x         = (const float*)d_in[0];
    const float* positions = (const float*)d_in[1];
    const int*   nbmap     = (const int*)d_in[2];
    const float* emb       = (const float*)d_in[3];
    const float* W1        = (const float*)d_in[4];
    const float* b1        = (const float*)d_in[5];
    const float* W2        = (const float*)d_in[6];
    const float* b2        = (const float*)d_in[7];
    const float* W3        = (const float*)d_in[8];
    const float* b3        = (const float*)d_in[9];
    const float* mu        = (const float*)d_in[10];
    const float* sd        = (const float*)d_in[11];
    float* out = (float*)d_out;

    int npts = in_sizes[0] / 2;
    size_t latB = (size_t)npts * 128;
    size_t need = latB + 32768;
    if (ws_size >= need) {
        unsigned char* ws = (unsigned char*)d_ws;
        unsigned* w1hi = (unsigned*)(ws + latB);
        unsigned* w1lo = (unsigned*)(ws + latB + 4096);
        unsigned* w2hi = (unsigned*)(ws + latB + 8192);
        unsigned* w2lo = (unsigned*)(ws + latB + 16384);
        unsigned* w3hi = (unsigned*)(ws + latB + 24576);
        unsigned* w3lo = (unsigned*)(ws + latB + 26624);
        prep_weights<<<1, 256, 0, stream>>>(W1, W2, W3, w1hi, w1lo, w2hi, w2lo, w3hi, w3lo);
        int g1 = (npts * 8 + 255) / 256;
        gather_latent<<<g1, 256, 0, stream>>>(x, positions, nbmap, emb, ws, npts);
        int g2 = (npts + 255) / 256;
        mlp_mfma<<<g2, 256, 0, stream>>>(ws, w1hi, w1lo, w2hi, w2lo, w3hi, w3lo,
                                         b1, b2, b3, mu, sd, out, npts);
    } else {
        int blocks = (npts + 127) / 128;
        fused_fallback<<<blocks, 128, 0, stream>>>(x, positions, nbmap, emb,
                                                   W1, b1, W2, b2, W3, b3, mu, sd, out, npts);
    }
}